// Round 5
// baseline (457.300 us; speedup 1.0000x reference)
//
#include <hip/hip_runtime.h>

// N=50000, E=400000, D=128, DE=64, H=8
#define D 128
#define DE 64
#define SLOPE 0.2f
#define EPS 1e-5f

typedef float f32x4 __attribute__((ext_vector_type(4)));
typedef short bf16x8 __attribute__((ext_vector_type(8)));
typedef unsigned short ushort;

__device__ __forceinline__ float lrelu(float x) { return x > 0.f ? x : SLOPE * x; }

// fp32 -> bf16 RNE
__device__ __forceinline__ ushort f2bf(float x) {
  union { float f; unsigned u; } c; c.f = x;
  unsigned r = c.u + 0x7FFFu + ((c.u >> 16) & 1u);
  return (ushort)(r >> 16);
}
__device__ __forceinline__ float bf2f(unsigned u) {
  return __uint_as_float(u << 16);
}

// ---------------------------------------------------------------------------
// K0: fold weights + pack all bf16 operand tables.
__global__ __launch_bounds__(128) void fold_pack(
    const float* __restrict__ Wq, const float* __restrict__ Wk,
    const float* __restrict__ We, const float* __restrict__ A1,
    const float* __restrict__ bq, const float* __restrict__ bk,
    const float* __restrict__ be, const float* __restrict__ b1,
    const float* __restrict__ Wn, const float* __restrict__ Wv,
    ushort* __restrict__ AfqT, ushort* __restrict__ AfkT,
    ushort* __restrict__ AfeT, float* __restrict__ bfold,
    ushort* __restrict__ WnT, ushort* __restrict__ WvT) {
  int r = blockIdx.x;
  int j = threadIdx.x;
  if (r < 128) {
    float acc = 0.f;
    for (int t = 0; t < 128; ++t) acc += Wq[r * 128 + t] * A1[t * 128 + j];
    AfqT[j * 128 + r] = f2bf(acc);
  } else if (r < 256) {
    int k = r - 128;
    float acc = 0.f;
    for (int t = 0; t < 128; ++t) acc += Wk[k * 128 + t] * A1[(128 + t) * 128 + j];
    AfkT[j * 128 + k] = f2bf(acc);
  } else if (r < 320) {
    int k = r - 256;
    float acc = 0.f;
    for (int t = 0; t < 128; ++t) acc += We[k * 128 + t] * A1[(256 + t) * 128 + j];
    AfeT[j * 64 + k] = f2bf(acc);
  } else if (r == 320) {
    float acc = b1[j];
    for (int t = 0; t < 128; ++t) {
      acc += bq[t] * A1[t * 128 + j];
      acc += bk[t] * A1[(128 + t) * 128 + j];
      acc += be[t] * A1[(256 + t) * 128 + j];
    }
    bfold[j] = acc;
  } else if (r < 449) {
    int c = r - 321;
    WnT[c * 128 + j] = f2bf(Wn[j * 128 + c]);
  } else {
    int c = r - 449;
    WvT[c * 128 + j] = f2bf(Wv[j * 128 + c]);
  }
}

// Fused: X fp32 -> bf16  +  deg histogram
__global__ __launch_bounds__(256) void cvt_count(
    const float* __restrict__ X, ushort* __restrict__ Xb, int n4,
    const int* __restrict__ src, int* __restrict__ deg, int E) {
  int i = blockIdx.x * 256 + threadIdx.x;
  if (i < n4) {
    float4 f = ((const float4*)X)[i];
    union { ushort us[4]; uint2 v; } u;
    u.us[0] = f2bf(f.x); u.us[1] = f2bf(f.y);
    u.us[2] = f2bf(f.z); u.us[3] = f2bf(f.w);
    ((uint2*)Xb)[i] = u.v;
  }
  if (i < E) atomicAdd(&deg[src[i]], 1);
}

// ---------------------------------------------------------------------------
// K1: node GEMMs via MFMA.
//  y=0: h = X@Wn+bn (fp32, d_out)       y=1: vb = bf16(X@Wv+bv)
//  y=2: q2p = bf16(X@Af_q) permuted     y=3: k2p = bf16(X@Af_k) permuted
__global__ __launch_bounds__(256, 2) void node_gemm_mfma(
    const ushort* __restrict__ Xb, const ushort* __restrict__ WnT,
    const ushort* __restrict__ WvT, const ushort* __restrict__ AfqT,
    const ushort* __restrict__ AfkT, const float* __restrict__ bn,
    const float* __restrict__ bv, float* __restrict__ h,
    ushort* __restrict__ vb, ushort* __restrict__ q2p,
    ushort* __restrict__ k2p, int Nn) {
  __shared__ ushort As[256 * 40];
  __shared__ ushort Bs[128 * 40];
  __shared__ float bS[128];
  const ushort* WT;
  const float* bb = nullptr;
  float* O = nullptr;
  ushort* Ob = nullptr;
  int mode;
  switch (blockIdx.y) {
    case 0: WT = WnT; bb = bn; O = h; mode = 0; break;
    case 1: WT = WvT; bb = bv; Ob = vb; mode = 1; break;
    case 2: WT = AfqT; Ob = q2p; mode = 2; break;
    default: WT = AfkT; Ob = k2p; mode = 2; break;
  }
  const int t = threadIdx.x;
  if (t < 128) bS[t] = bb ? bb[t] : 0.f;
  const int seg = t & 3, arow = t >> 2;
  const int m0 = blockIdx.x * 256;
  int rIdx[4];
#pragma unroll
  for (int l = 0; l < 4; ++l) rIdx[l] = min(m0 + arow + 64 * l, Nn - 1);
  uint4 avA[4], avB[2];
#pragma unroll
  for (int l = 0; l < 4; ++l)
    avA[l] = *(const uint4*)(Xb + (size_t)rIdx[l] * 128 + seg * 8);
#pragma unroll
  for (int l = 0; l < 2; ++l)
    avB[l] = *(const uint4*)(WT + (arow + 64 * l) * 128 + seg * 8);
  f32x4 acc[4][8];
#pragma unroll
  for (int mt = 0; mt < 4; ++mt)
#pragma unroll
    for (int nt = 0; nt < 8; ++nt) acc[mt][nt] = (f32x4)(0.f);
  const int lane = t & 63, wv = t >> 6, l15 = lane & 15, quad = lane >> 4;
  for (int ch = 0; ch < 4; ++ch) {
#pragma unroll
    for (int l = 0; l < 4; ++l)
      *(uint4*)&As[(arow + 64 * l) * 40 + seg * 8] = avA[l];
#pragma unroll
    for (int l = 0; l < 2; ++l)
      *(uint4*)&Bs[(arow + 64 * l) * 40 + seg * 8] = avB[l];
    __syncthreads();
    if (ch < 3) {
      int o = (ch + 1) * 32 + seg * 8;
#pragma unroll
      for (int l = 0; l < 4; ++l)
        avA[l] = *(const uint4*)(Xb + (size_t)rIdx[l] * 128 + o);
#pragma unroll
      for (int l = 0; l < 2; ++l)
        avB[l] = *(const uint4*)(WT + (arow + 64 * l) * 128 + o);
    }
    bf16x8 af[4];
#pragma unroll
    for (int mt = 0; mt < 4; ++mt)
      af[mt] = *(const bf16x8*)&As[(wv * 64 + mt * 16 + l15) * 40 + quad * 8];
#pragma unroll
    for (int nt = 0; nt < 8; ++nt) {
      bf16x8 bfr = *(const bf16x8*)&Bs[(nt * 16 + l15) * 40 + quad * 8];
#pragma unroll
      for (int mt = 0; mt < 4; ++mt)
        acc[mt][nt] =
            __builtin_amdgcn_mfma_f32_16x16x32_bf16(af[mt], bfr, acc[mt][nt], 0, 0, 0);
    }
    __syncthreads();
  }
#pragma unroll
  for (int mt = 0; mt < 4; ++mt) {
    int rowb = m0 + wv * 64 + mt * 16 + quad * 4;
#pragma unroll
    for (int nt = 0; nt < 8; ++nt) {
      int col = nt * 16 + l15;
      float b = bS[col];
#pragma unroll
      for (int r = 0; r < 4; ++r) {
        int rg = rowb + r;
        if (rg < Nn) {
          if (mode == 0)      O[(size_t)rg * 128 + col] = acc[mt][nt][r] + b;
          else if (mode == 1) Ob[(size_t)rg * 128 + col] = f2bf(acc[mt][nt][r] + b);
          else                Ob[(size_t)rg * 128 + l15 * 8 + nt] = f2bf(acc[mt][nt][r]);
        }
      }
    }
  }
}

// ---------------------------------------------------------------------------
// K2: streaming edge pipeline, pipelined epilogue gathers.
__global__ __launch_bounds__(256, 2) void edge_fused3(
    const float* __restrict__ EF, const ushort* __restrict__ AfeT,
    const float* __restrict__ bfold, const float* __restrict__ A2,
    const float* __restrict__ b2, const ushort* __restrict__ q2p,
    const ushort* __restrict__ k2p, const int* __restrict__ src,
    const int* __restrict__ tgt, float* __restrict__ s_out, int E) {
  __shared__ ushort As[256 * 40];
  __shared__ ushort Bs[128 * 40];
  __shared__ float A2s[128 * 9];
  __shared__ float bfS[128];
  __shared__ float b2s[8];
  const int t = threadIdx.x;
  const int e0 = blockIdx.x * 256;
  const int lane = t & 63, wv = t >> 6, l15 = lane & 15, quad = lane >> 4;

  // per-thread edge indices for the epilogue: issue these loads first
  int siA[16], tiA[16];
#pragma unroll
  for (int mt = 0; mt < 4; ++mt)
#pragma unroll
    for (int r = 0; r < 4; ++r) {
      int e = min(e0 + wv * 64 + mt * 16 + quad * 4 + r, E - 1);
      siA[mt * 4 + r] = src[e];
      tiA[mt * 4 + r] = tgt[e];
    }
  {
    if (t < 128) bfS[t] = bfold[t];
    if (t < 8) b2s[t] = b2[t];
#pragma unroll
    for (int l = 0; l < 4; ++l) {
      int i = t + l * 256;
      A2s[(i >> 3) * 9 + (i & 7)] = A2[i];
    }
  }
  const int seg = t & 3, arow = t >> 2;
  int ecl[4];
#pragma unroll
  for (int l = 0; l < 4; ++l) ecl[l] = min(e0 + arow + 64 * l, E - 1);
  uint4 avA[4], avB[2];
#pragma unroll
  for (int l = 0; l < 4; ++l) {
    const float* p = EF + (size_t)ecl[l] * 64 + seg * 8;
    float4 f0 = *(const float4*)p;
    float4 f1 = *(const float4*)(p + 4);
    union { ushort us[8]; uint4 v; } u;
    u.us[0] = f2bf(f0.x); u.us[1] = f2bf(f0.y);
    u.us[2] = f2bf(f0.z); u.us[3] = f2bf(f0.w);
    u.us[4] = f2bf(f1.x); u.us[5] = f2bf(f1.y);
    u.us[6] = f2bf(f1.z); u.us[7] = f2bf(f1.w);
    avA[l] = u.v;
  }
#pragma unroll
  for (int l = 0; l < 2; ++l)
    avB[l] = *(const uint4*)(AfeT + (arow + 64 * l) * 64 + seg * 8);
  f32x4 acc[4][8];
#pragma unroll
  for (int mt = 0; mt < 4; ++mt)
#pragma unroll
    for (int nt = 0; nt < 8; ++nt) acc[mt][nt] = (f32x4)(0.f);

#pragma unroll
  for (int ch = 0; ch < 2; ++ch) {
#pragma unroll
    for (int l = 0; l < 4; ++l)
      *(uint4*)&As[(arow + 64 * l) * 40 + seg * 8] = avA[l];
#pragma unroll
    for (int l = 0; l < 2; ++l)
      *(uint4*)&Bs[(arow + 64 * l) * 40 + seg * 8] = avB[l];
    __syncthreads();
    if (ch == 0) {
      int o = 32 + seg * 8;
#pragma unroll
      for (int l = 0; l < 4; ++l) {
        const float* p = EF + (size_t)ecl[l] * 64 + o;
        float4 f0 = *(const float4*)p;
        float4 f1 = *(const float4*)(p + 4);
        union { ushort us[8]; uint4 v; } u;
        u.us[0] = f2bf(f0.x); u.us[1] = f2bf(f0.y);
        u.us[2] = f2bf(f0.z); u.us[3] = f2bf(f0.w);
        u.us[4] = f2bf(f1.x); u.us[5] = f2bf(f1.y);
        u.us[6] = f2bf(f1.z); u.us[7] = f2bf(f1.w);
        avA[l] = u.v;
      }
#pragma unroll
      for (int l = 0; l < 2; ++l)
        avB[l] = *(const uint4*)(AfeT + (arow + 64 * l) * 64 + o);
    }
    bf16x8 af[4];
#pragma unroll
    for (int mt = 0; mt < 4; ++mt)
      af[mt] = *(const bf16x8*)&As[(wv * 64 + mt * 16 + l15) * 40 + quad * 8];
#pragma unroll
    for (int nt = 0; nt < 8; ++nt) {
      bf16x8 bfr = *(const bf16x8*)&Bs[(nt * 16 + l15) * 40 + quad * 8];
#pragma unroll
      for (int mt = 0; mt < 4; ++mt)
        acc[mt][nt] =
            __builtin_amdgcn_mfma_f32_16x16x32_bf16(af[mt], bfr, acc[mt][nt], 0, 0, 0);
    }
    if (ch == 0) __syncthreads();
  }

  // pass 1: pipelined gathers -> hmid = lrelu(e2 + q2 + k2 + bfold) in acc
  float bfv[8];
#pragma unroll
  for (int nt = 0; nt < 8; ++nt) bfv[nt] = bfS[nt * 16 + l15];
  uint4 qv[2][4], kv[2][4];
#pragma unroll
  for (int r = 0; r < 4; ++r) {
    qv[0][r] = *(const uint4*)(q2p + (size_t)siA[r] * 128 + l15 * 8);
    kv[0][r] = *(const uint4*)(k2p + (size_t)tiA[r] * 128 + l15 * 8);
  }
#pragma unroll
  for (int mt = 0; mt < 4; ++mt) {
    int cur = mt & 1;
    if (mt < 3) {
#pragma unroll
      for (int r = 0; r < 4; ++r) {
        qv[cur ^ 1][r] = *(const uint4*)(q2p + (size_t)siA[(mt + 1) * 4 + r] * 128 + l15 * 8);
        kv[cur ^ 1][r] = *(const uint4*)(k2p + (size_t)tiA[(mt + 1) * 4 + r] * 128 + l15 * 8);
      }
    }
#pragma unroll
    for (int r = 0; r < 4; ++r) {
      const ushort* qs = (const ushort*)&qv[cur][r];
      const ushort* ks = (const ushort*)&kv[cur][r];
#pragma unroll
      for (int nt = 0; nt < 8; ++nt)
        acc[mt][nt][r] =
            lrelu(acc[mt][nt][r] + bf2f(qs[nt]) + bf2f(ks[nt]) + bfv[nt]);
    }
  }
  // pass 2: head stage  s = mean_h lrelu(hmid @ A2 + b2)
  float tacc[4][4];
#pragma unroll
  for (int mt = 0; mt < 4; ++mt)
#pragma unroll
    for (int r = 0; r < 4; ++r) tacc[mt][r] = 0.f;
  for (int hh = 0; hh < 8; ++hh) {
    float a2v[8];
#pragma unroll
    for (int nt = 0; nt < 8; ++nt) a2v[nt] = A2s[nt * 144 + l15 * 9 + hh];
    float b2h = b2s[hh];
#pragma unroll
    for (int mt = 0; mt < 4; ++mt)
#pragma unroll
      for (int r = 0; r < 4; ++r) {
        float p = 0.f;
#pragma unroll
        for (int nt = 0; nt < 8; ++nt) p += acc[mt][nt][r] * a2v[nt];
        p += __shfl_xor(p, 1);
        p += __shfl_xor(p, 2);
        p += __shfl_xor(p, 4);
        p += __shfl_xor(p, 8);
        tacc[mt][r] += lrelu(p + b2h);
      }
  }
  if (l15 == 0) {
#pragma unroll
    for (int mt = 0; mt < 4; ++mt)
#pragma unroll
      for (int r = 0; r < 4; ++r) {
        int e = e0 + wv * 64 + mt * 16 + quad * 4 + r;
        if (e < E) s_out[e] = tacc[mt][r] * 0.125f;
      }
  }
}

// ---------------------------------------------------------------------------
// K3/K4: global softmax reduction
__global__ __launch_bounds__(256) void softmax_partial(
    const float* __restrict__ s, int E, float2* __restrict__ part) {
  __shared__ float mS[256], sS[256];
  int tid = threadIdx.x;
  float m = -1e30f, sum = 0.f;
  for (int i = blockIdx.x * 256 + tid; i < E; i += gridDim.x * 256) {
    float x = s[i];
    if (x > m) {
      sum = sum * __expf(m - x) + 1.f;
      m = x;
    } else {
      sum += __expf(x - m);
    }
  }
  mS[tid] = m;
  sS[tid] = sum;
  __syncthreads();
  for (int off = 128; off > 0; off >>= 1) {
    if (tid < off) {
      float m1 = mS[tid], s1 = sS[tid];
      float m2 = mS[tid + off], s2 = sS[tid + off];
      float M = fmaxf(m1, m2);
      mS[tid] = M;
      sS[tid] = s1 * __expf(m1 - M) + s2 * __expf(m2 - M);
    }
    __syncthreads();
  }
  if (tid == 0) part[blockIdx.x] = make_float2(mS[0], sS[0]);
}

__global__ __launch_bounds__(256) void softmax_final(
    const float2* __restrict__ part, int nPart, float* __restrict__ MS) {
  __shared__ float mS[256], sS[256];
  int tid = threadIdx.x;
  float m = -1e30f, sum = 0.f;
  for (int i = tid; i < nPart; i += 256) {
    float2 p = part[i];
    float M = fmaxf(m, p.x);
    sum = sum * __expf(m - M) + p.y * __expf(p.x - M);
    m = M;
  }
  mS[tid] = m;
  sS[tid] = sum;
  __syncthreads();
  for (int off = 128; off > 0; off >>= 1) {
    if (tid < off) {
      float m1 = mS[tid], s1 = sS[tid];
      float m2 = mS[tid + off], s2 = sS[tid + off];
      float M = fmaxf(m1, m2);
      mS[tid] = M;
      sS[tid] = s1 * __expf(m1 - M) + s2 * __expf(m2 - M);
    }
    __syncthreads();
  }
  if (tid == 0) {
    MS[0] = mS[0];
    MS[1] = 1.f / sS[0];
  }
}

// ---------------------------------------------------------------------------
// CSR build
__global__ __launch_bounds__(256) void scan1(const int* __restrict__ deg,
                                             int* __restrict__ incl,
                                             int* __restrict__ bsum, int N) {
  __shared__ int sh[256];
  int tid = threadIdx.x;
  int i = blockIdx.x * 256 + tid;
  sh[tid] = (i < N) ? deg[i] : 0;
  __syncthreads();
  for (int off = 1; off < 256; off <<= 1) {
    int tv = (tid >= off) ? sh[tid - off] : 0;
    __syncthreads();
    sh[tid] += tv;
    __syncthreads();
  }
  if (i < N) incl[i] = sh[tid];
  if (tid == 255) bsum[blockIdx.x] = sh[255];
}

__global__ __launch_bounds__(256) void scan2(int* __restrict__ bsum, int nb) {
  __shared__ int sh[256];
  int tid = threadIdx.x;
  sh[tid] = (tid < nb) ? bsum[tid] : 0;
  __syncthreads();
  for (int off = 1; off < 256; off <<= 1) {
    int tv = (tid >= off) ? sh[tid - off] : 0;
    __syncthreads();
    sh[tid] += tv;
    __syncthreads();
  }
  if (tid < nb) bsum[tid] = sh[tid];
}

__global__ __launch_bounds__(256) void scan3(const int* __restrict__ deg,
                                             const int* __restrict__ incl,
                                             const int* __restrict__ bsum,
                                             int* __restrict__ offs,
                                             int* __restrict__ cursor, int N,
                                             int E) {
  int i = blockIdx.x * 256 + threadIdx.x;
  if (i >= N) return;
  int base = (blockIdx.x > 0) ? bsum[blockIdx.x - 1] : 0;
  int ex = incl[i] - deg[i] + base;
  offs[i] = ex;
  cursor[i] = ex;
  if (i == N - 1) offs[N] = E;
}

__global__ __launch_bounds__(256) void fill_csr(
    const int* __restrict__ src, const int* __restrict__ tgt,
    const float* __restrict__ s, int* __restrict__ cursor,
    int2* __restrict__ cwt, int E) {
  int e = blockIdx.x * 256 + threadIdx.x;
  if (e >= E) return;
  int s_ = src[e];
  int j = atomicAdd(&cursor[s_], 1);
  cwt[j] = make_int2(tgt[e], __float_as_int(s[e]));
}

// ---------------------------------------------------------------------------
// K5: fused gather (bf16 v) + softmax-normalize + layernorm.
__global__ __launch_bounds__(256) void gather_ln(
    const int* __restrict__ offs, const int2* __restrict__ cwt,
    const ushort* __restrict__ vb, const float* __restrict__ MS,
    const float* __restrict__ gamma, const float* __restrict__ beta,
    float* __restrict__ y, int N) {
  int tid = threadIdx.x;
  int n = blockIdx.x * 4 + (tid >> 6);
  if (n >= N) return;  // wave-uniform
  int lane = tid & 63;
  float M = MS[0], inv = MS[1];
  int beg = offs[n], end = offs[n + 1];
  float a0 = 0.f, a1 = 0.f;
  int j = beg;
  for (; j + 1 < end; j += 2) {
    int2 p0 = cwt[j], p1 = cwt[j + 1];
    float w0 = __expf(__int_as_float(p0.y) - M) * inv;
    float w1 = __expf(__int_as_float(p1.y) - M) * inv;
    unsigned u0 = *(const unsigned*)(vb + (size_t)p0.x * 128 + lane * 2);
    unsigned u1 = *(const unsigned*)(vb + (size_t)p1.x * 128 + lane * 2);
    a0 += w0 * bf2f(u0 & 0xffffu) + w1 * bf2f(u1 & 0xffffu);
    a1 += w0 * bf2f(u0 >> 16) + w1 * bf2f(u1 >> 16);
  }
  if (j < end) {
    int2 p = cwt[j];
    float w = __expf(__int_as_float(p.y) - M) * inv;
    unsigned u = *(const unsigned*)(vb + (size_t)p.x * 128 + lane * 2);
    a0 += w * bf2f(u & 0xffffu);
    a1 += w * bf2f(u >> 16);
  }
  size_t base = (size_t)n * 128 + lane * 2;
  float2 hv = *(const float2*)(y + base);
  float y0 = hv.x + a0, y1 = hv.y + a1;
  float sum = y0 + y1, ssq = y0 * y0 + y1 * y1;
#pragma unroll
  for (int off = 1; off < 64; off <<= 1) {
    sum += __shfl_xor(sum, off);
    ssq += __shfl_xor(ssq, off);
  }
  float mu = sum * (1.f / 128.f);
  float var = ssq * (1.f / 128.f) - mu * mu;
  float rstd = rsqrtf(var + EPS);
  float2 g = *(const float2*)(gamma + lane * 2);
  float2 bt = *(const float2*)(beta + lane * 2);
  float2 out;
  out.x = g.x * (y0 - mu) * rstd + bt.x;
  out.y = g.y * (y1 - mu) * rstd + bt.y;
  *(float2*)(y + base) = out;
}

// ---------------------------------------------------------------------------
extern "C" void kernel_launch(void* const* d_in, const int* in_sizes, int n_in,
                              void* d_out, int out_size, void* d_ws,
                              size_t ws_size, hipStream_t stream) {
  const float* X  = (const float*)d_in[0];
  const float* EF = (const float*)d_in[1];
  const float* Wn = (const float*)d_in[2];
  const float* bn = (const float*)d_in[3];
  const float* Wq = (const float*)d_in[4];
  const float* bq = (const float*)d_in[5];
  const float* Wk = (const float*)d_in[6];
  const float* bk = (const float*)d_in[7];
  const float* Wv = (const float*)d_in[8];
  const float* bv = (const float*)d_in[9];
  const float* We = (const float*)d_in[10];
  const float* be = (const float*)d_in[11];
  const float* A1 = (const float*)d_in[12];
  const float* b1 = (const float*)d_in[13];
  const float* A2 = (const float*)d_in[14];
  const float* b2 = (const float*)d_in[15];
  const float* gamma = (const float*)d_in[16];
  const float* beta  = (const float*)d_in[17];
  const int* ei = (const int*)d_in[18];

  int N = in_sizes[0] / D;   // 50000
  int E = in_sizes[1] / DE;  // 400000
  const int* src = ei;
  const int* tgt = ei + E;

  float* h = (float*)d_out;  // h accumulated/normalized in place
  float* ws = (float*)d_ws;
  float* sbuf  = ws;                                   // E f32
  float2* part = (float2*)(sbuf + E);                  // 1024
  float* MS    = (float*)(part + 1024);                // 4
  float* bfold = MS + 4;                               // 128
  ushort* Xb   = (ushort*)(bfold + 128);               // N*128
  ushort* vb   = Xb + (size_t)N * D;                   // N*128 (bf16 v)
  ushort* q2p  = vb + (size_t)N * D;                   // N*128
  ushort* k2p  = q2p + (size_t)N * D;                  // N*128
  ushort* AfqT = k2p + (size_t)N * D;                  // 128*128
  ushort* AfkT = AfqT + 128 * 128;                     // 128*128
  ushort* AfeT = AfkT + 128 * 128;                     // 128*64
  ushort* WnT  = AfeT + 128 * 64;                      // 128*128
  ushort* WvT  = WnT + 128 * 128;                      // 128*128
  int* deg    = (int*)(WvT + 128 * 128);               // N
  int* incl   = deg + N;                               // N
  int* bsum   = incl + N;                              // 256
  int* cursor = bsum + 256;                            // N
  int* offs   = cursor + N;                            // N+2
  int2* cwt   = (int2*)(offs + N + 2);                 // E

  int nbScan = (N + 255) / 256;  // 196 (<= 256)
  int n4 = N * D / 4;

  hipMemsetAsync(deg, 0, (size_t)N * sizeof(int), stream);
  fold_pack<<<577, 128, 0, stream>>>(Wq, Wk, We, A1, bq, bk, be, b1, Wn, Wv,
                                     AfqT, AfkT, AfeT, bfold, WnT, WvT);
  cvt_count<<<(n4 + 255) / 256, 256, 0, stream>>>(X, Xb, n4, src, deg, E);
  scan1<<<nbScan, 256, 0, stream>>>(deg, incl, bsum, N);
  scan2<<<1, 256, 0, stream>>>(bsum, nbScan);
  scan3<<<nbScan, 256, 0, stream>>>(deg, incl, bsum, offs, cursor, N, E);
  node_gemm_mfma<<<dim3((N + 255) / 256, 4), 256, 0, stream>>>(
      Xb, WnT, WvT, AfqT, AfkT, bn, bv, h, vb, q2p, k2p, N);
  edge_fused3<<<(E + 255) / 256, 256, 0, stream>>>(EF, AfeT, bfold, A2, b2,
                                                   q2p, k2p, src, tgt, sbuf, E);
  softmax_partial<<<1024, 256, 0, stream>>>(sbuf, E, part);
  softmax_final<<<1, 256, 0, stream>>>(part, 1024, MS);
  fill_csr<<<(E + 255) / 256, 256, 0, stream>>>(src, tgt, sbuf, cursor, cwt, E);
  gather_ln<<<(N + 3) / 4, 256, 0, stream>>>(offs, cwt, vb, MS, gamma, beta, h,
                                             N);
}

// Round 6
// 384.594 us; speedup vs baseline: 1.1890x; 1.1890x over previous
//
#include <hip/hip_runtime.h>

// N=50000, E=400000, D=128, DE=64, H=8
#define D 128
#define DE 64
#define SLOPE 0.2f
#define EPS 1e-5f

typedef float f32x4 __attribute__((ext_vector_type(4)));
typedef short bf16x8 __attribute__((ext_vector_type(8)));
typedef unsigned short ushort;

__device__ __forceinline__ float lrelu(float x) { return x > 0.f ? x : SLOPE * x; }

// fp32 -> bf16 RNE
__device__ __forceinline__ ushort f2bf(float x) {
  union { float f; unsigned u; } c; c.f = x;
  unsigned r = c.u + 0x7FFFu + ((c.u >> 16) & 1u);
  return (ushort)(r >> 16);
}
__device__ __forceinline__ float bf2f(unsigned u) {
  return __uint_as_float(u << 16);
}
__device__ __forceinline__ uint4 cvt8(const float* p) {
  float4 f0 = *(const float4*)p;
  float4 f1 = *(const float4*)(p + 4);
  union { ushort us[8]; uint4 v; } u;
  u.us[0] = f2bf(f0.x); u.us[1] = f2bf(f0.y);
  u.us[2] = f2bf(f0.z); u.us[3] = f2bf(f0.w);
  u.us[4] = f2bf(f1.x); u.us[5] = f2bf(f1.y);
  u.us[6] = f2bf(f1.z); u.us[7] = f2bf(f1.w);
  return u.v;
}

// ---------------------------------------------------------------------------
// K0: fold weights + pack bf16 tables + deg histogram (blocks >= 577).
__global__ __launch_bounds__(128) void fold_pack(
    const float* __restrict__ Wq, const float* __restrict__ Wk,
    const float* __restrict__ We, const float* __restrict__ A1,
    const float* __restrict__ bq, const float* __restrict__ bk,
    const float* __restrict__ be, const float* __restrict__ b1,
    const float* __restrict__ Wn, const float* __restrict__ Wv,
    ushort* __restrict__ AfqT, ushort* __restrict__ AfkT,
    ushort* __restrict__ AfeT, float* __restrict__ bfold,
    ushort* __restrict__ WnT, ushort* __restrict__ WvT,
    const int* __restrict__ src, int* __restrict__ deg, int E) {
  int r = blockIdx.x;
  int j = threadIdx.x;
  if (r < 128) {
    float acc = 0.f;
    for (int t = 0; t < 128; ++t) acc += Wq[r * 128 + t] * A1[t * 128 + j];
    AfqT[j * 128 + r] = f2bf(acc);
  } else if (r < 256) {
    int k = r - 128;
    float acc = 0.f;
    for (int t = 0; t < 128; ++t) acc += Wk[k * 128 + t] * A1[(128 + t) * 128 + j];
    AfkT[j * 128 + k] = f2bf(acc);
  } else if (r < 320) {
    int k = r - 256;
    float acc = 0.f;
    for (int t = 0; t < 128; ++t) acc += We[k * 128 + t] * A1[(256 + t) * 128 + j];
    AfeT[j * 64 + k] = f2bf(acc);
  } else if (r == 320) {
    float acc = b1[j];
    for (int t = 0; t < 128; ++t) {
      acc += bq[t] * A1[t * 128 + j];
      acc += bk[t] * A1[(128 + t) * 128 + j];
      acc += be[t] * A1[(256 + t) * 128 + j];
    }
    bfold[j] = acc;
  } else if (r < 449) {
    int c = r - 321;
    WnT[c * 128 + j] = f2bf(Wn[j * 128 + c]);
  } else if (r < 577) {
    int c = r - 449;
    WvT[c * 128 + j] = f2bf(Wv[j * 128 + c]);
  } else {
    int i = (r - 577) * 128 + j;
    if (i < E) atomicAdd(&deg[src[i]], 1);
  }
}

// ---------------------------------------------------------------------------
// K1: node GEMMs via MFMA, X converted fp32->bf16 inline.
//  y=0: h = X@Wn+bn (fp32, d_out)       y=1: vb = bf16(X@Wv+bv)
//  y=2: q2p = bf16(X@Af_q) permuted     y=3: k2p = bf16(X@Af_k) permuted
__global__ __launch_bounds__(256, 2) void node_gemm_mfma(
    const float* __restrict__ X, const ushort* __restrict__ WnT,
    const ushort* __restrict__ WvT, const ushort* __restrict__ AfqT,
    const ushort* __restrict__ AfkT, const float* __restrict__ bn,
    const float* __restrict__ bv, float* __restrict__ h,
    ushort* __restrict__ vb, ushort* __restrict__ q2p,
    ushort* __restrict__ k2p, int Nn) {
  __shared__ ushort As[256 * 40];
  __shared__ ushort Bs[128 * 40];
  __shared__ float bS[128];
  const ushort* WT;
  const float* bb = nullptr;
  float* O = nullptr;
  ushort* Ob = nullptr;
  int mode;
  switch (blockIdx.y) {
    case 0: WT = WnT; bb = bn; O = h; mode = 0; break;
    case 1: WT = WvT; bb = bv; Ob = vb; mode = 1; break;
    case 2: WT = AfqT; Ob = q2p; mode = 2; break;
    default: WT = AfkT; Ob = k2p; mode = 2; break;
  }
  const int t = threadIdx.x;
  if (t < 128) bS[t] = bb ? bb[t] : 0.f;
  const int seg = t & 3, arow = t >> 2;
  const int m0 = blockIdx.x * 256;
  int rIdx[4];
#pragma unroll
  for (int l = 0; l < 4; ++l) rIdx[l] = min(m0 + arow + 64 * l, Nn - 1);
  uint4 avA[4], avB[2];
#pragma unroll
  for (int l = 0; l < 4; ++l)
    avA[l] = cvt8(X + (size_t)rIdx[l] * 128 + seg * 8);
#pragma unroll
  for (int l = 0; l < 2; ++l)
    avB[l] = *(const uint4*)(WT + (arow + 64 * l) * 128 + seg * 8);
  f32x4 acc[4][8];
#pragma unroll
  for (int mt = 0; mt < 4; ++mt)
#pragma unroll
    for (int nt = 0; nt < 8; ++nt) acc[mt][nt] = (f32x4)(0.f);
  const int lane = t & 63, wv = t >> 6, l15 = lane & 15, quad = lane >> 4;
  for (int ch = 0; ch < 4; ++ch) {
#pragma unroll
    for (int l = 0; l < 4; ++l)
      *(uint4*)&As[(arow + 64 * l) * 40 + seg * 8] = avA[l];
#pragma unroll
    for (int l = 0; l < 2; ++l)
      *(uint4*)&Bs[(arow + 64 * l) * 40 + seg * 8] = avB[l];
    __syncthreads();
    if (ch < 3) {
      int o = (ch + 1) * 32 + seg * 8;
#pragma unroll
      for (int l = 0; l < 4; ++l)
        avA[l] = cvt8(X + (size_t)rIdx[l] * 128 + o);
#pragma unroll
      for (int l = 0; l < 2; ++l)
        avB[l] = *(const uint4*)(WT + (arow + 64 * l) * 128 + o);
    }
    bf16x8 af[4];
#pragma unroll
    for (int mt = 0; mt < 4; ++mt)
      af[mt] = *(const bf16x8*)&As[(wv * 64 + mt * 16 + l15) * 40 + quad * 8];
#pragma unroll
    for (int nt = 0; nt < 8; ++nt) {
      bf16x8 bfr = *(const bf16x8*)&Bs[(nt * 16 + l15) * 40 + quad * 8];
#pragma unroll
      for (int mt = 0; mt < 4; ++mt)
        acc[mt][nt] =
            __builtin_amdgcn_mfma_f32_16x16x32_bf16(af[mt], bfr, acc[mt][nt], 0, 0, 0);
    }
    __syncthreads();
  }
#pragma unroll
  for (int mt = 0; mt < 4; ++mt) {
    int rowb = m0 + wv * 64 + mt * 16 + quad * 4;
#pragma unroll
    for (int nt = 0; nt < 8; ++nt) {
      int col = nt * 16 + l15;
      float b = bS[col];
#pragma unroll
      for (int r = 0; r < 4; ++r) {
        int rg = rowb + r;
        if (rg < Nn) {
          if (mode == 0)      O[(size_t)rg * 128 + col] = acc[mt][nt][r] + b;
          else if (mode == 1) Ob[(size_t)rg * 128 + col] = f2bf(acc[mt][nt][r] + b);
          else                Ob[(size_t)rg * 128 + l15 * 8 + nt] = f2bf(acc[mt][nt][r]);
        }
      }
    }
  }
}

// ---------------------------------------------------------------------------
// K2: streaming edge pipeline, 128 edges/block (M=32/wave), fused CSR-fill
// and per-block softmax partial.
__global__ __launch_bounds__(256, 3) void edge_fused4(
    const float* __restrict__ EF, const ushort* __restrict__ AfeT,
    const float* __restrict__ bfold, const float* __restrict__ A2,
    const float* __restrict__ b2, const ushort* __restrict__ q2p,
    const ushort* __restrict__ k2p, const int* __restrict__ src,
    const int* __restrict__ tgt, int* __restrict__ cursor,
    int2* __restrict__ cwt, float2* __restrict__ part, int E) {
  __shared__ ushort As[128 * 40];
  __shared__ ushort Bs[128 * 40];
  __shared__ float A2s[128 * 9];
  __shared__ float bfS[128];
  __shared__ float b2s[8];
  __shared__ int sIdxS[128], sIdxT[128];
  __shared__ float redM[16], redS[16];
  const int t = threadIdx.x;
  const int e0 = blockIdx.x * 128;
  if (t < 128) {
    sIdxS[t] = src[min(e0 + t, E - 1)];
    bfS[t] = bfold[t];
  } else {
    sIdxT[t - 128] = tgt[min(e0 + t - 128, E - 1)];
  }
  if (t < 8) b2s[t] = b2[t];
#pragma unroll
  for (int l = 0; l < 4; ++l) {
    int i = t + l * 256;
    A2s[(i >> 3) * 9 + (i & 7)] = A2[i];
  }
  const int seg = t & 3, arow = t >> 2;  // arow in [0,64)
  int ecl[2];
#pragma unroll
  for (int l = 0; l < 2; ++l) ecl[l] = min(e0 + arow + 64 * l, E - 1);
  uint4 avA[2], avB[2];
#pragma unroll
  for (int l = 0; l < 2; ++l) {
    avA[l] = cvt8(EF + (size_t)ecl[l] * 64 + seg * 8);
    avB[l] = *(const uint4*)(AfeT + (arow + 64 * l) * 64 + seg * 8);
  }
  f32x4 acc[2][8];
#pragma unroll
  for (int mt = 0; mt < 2; ++mt)
#pragma unroll
    for (int nt = 0; nt < 8; ++nt) acc[mt][nt] = (f32x4)(0.f);
  const int lane = t & 63, wv = t >> 6, l15 = lane & 15, quad = lane >> 4;

#pragma unroll
  for (int ch = 0; ch < 2; ++ch) {
#pragma unroll
    for (int l = 0; l < 2; ++l) {
      *(uint4*)&As[(arow + 64 * l) * 40 + seg * 8] = avA[l];
      *(uint4*)&Bs[(arow + 64 * l) * 40 + seg * 8] = avB[l];
    }
    __syncthreads();
    if (ch == 0) {
      int o = 32 + seg * 8;
#pragma unroll
      for (int l = 0; l < 2; ++l) {
        avA[l] = cvt8(EF + (size_t)ecl[l] * 64 + o);
        avB[l] = *(const uint4*)(AfeT + (arow + 64 * l) * 64 + o);
      }
    }
    bf16x8 af[2];
#pragma unroll
    for (int mt = 0; mt < 2; ++mt)
      af[mt] = *(const bf16x8*)&As[(wv * 32 + mt * 16 + l15) * 40 + quad * 8];
#pragma unroll
    for (int nt = 0; nt < 8; ++nt) {
      bf16x8 bfr = *(const bf16x8*)&Bs[(nt * 16 + l15) * 40 + quad * 8];
#pragma unroll
      for (int mt = 0; mt < 2; ++mt)
        acc[mt][nt] =
            __builtin_amdgcn_mfma_f32_16x16x32_bf16(af[mt], bfr, acc[mt][nt], 0, 0, 0);
    }
    if (ch == 0) __syncthreads();
  }

  // epilogue: gather q2/k2 (indices from LDS), bias + lrelu
  float bfv[8];
#pragma unroll
  for (int nt = 0; nt < 8; ++nt) bfv[nt] = bfS[nt * 16 + l15];
#pragma unroll
  for (int mt = 0; mt < 2; ++mt) {
#pragma unroll
    for (int r = 0; r < 4; ++r) {
      int erow = wv * 32 + mt * 16 + quad * 4 + r;
      int si = sIdxS[erow], ti = sIdxT[erow];
      uint4 qv = *(const uint4*)(q2p + (size_t)si * 128 + l15 * 8);
      uint4 kv = *(const uint4*)(k2p + (size_t)ti * 128 + l15 * 8);
      const ushort* qs = (const ushort*)&qv;
      const ushort* ks = (const ushort*)&kv;
#pragma unroll
      for (int nt = 0; nt < 8; ++nt)
        acc[mt][nt][r] =
            lrelu(acc[mt][nt][r] + bf2f(qs[nt]) + bf2f(ks[nt]) + bfv[nt]);
    }
  }
  // head stage: s = mean_h lrelu(hmid @ A2 + b2)
  float tacc[2][4];
#pragma unroll
  for (int mt = 0; mt < 2; ++mt)
#pragma unroll
    for (int r = 0; r < 4; ++r) tacc[mt][r] = 0.f;
  for (int hh = 0; hh < 8; ++hh) {
    float a2v[8];
#pragma unroll
    for (int nt = 0; nt < 8; ++nt) a2v[nt] = A2s[nt * 144 + l15 * 9 + hh];
    float b2h = b2s[hh];
#pragma unroll
    for (int mt = 0; mt < 2; ++mt)
#pragma unroll
      for (int r = 0; r < 4; ++r) {
        float p = 0.f;
#pragma unroll
        for (int nt = 0; nt < 8; ++nt) p += acc[mt][nt][r] * a2v[nt];
        p += __shfl_xor(p, 1);
        p += __shfl_xor(p, 2);
        p += __shfl_xor(p, 4);
        p += __shfl_xor(p, 8);
        tacc[mt][r] += lrelu(p + b2h);
      }
  }
  // l15==0 lanes: 8 scores each -> CSR fill + block softmax partial
  if (l15 == 0) {
    float sc[8];
    float m = -1e30f;
#pragma unroll
    for (int mt = 0; mt < 2; ++mt)
#pragma unroll
      for (int r = 0; r < 4; ++r) {
        int i = mt * 4 + r;
        sc[i] = tacc[mt][r] * 0.125f;
        int e = e0 + wv * 32 + mt * 16 + quad * 4 + r;
        if (e < E) m = fmaxf(m, sc[i]);
      }
    float ssum = 0.f;
#pragma unroll
    for (int mt = 0; mt < 2; ++mt)
#pragma unroll
      for (int r = 0; r < 4; ++r) {
        int i = mt * 4 + r;
        int erow = wv * 32 + mt * 16 + quad * 4 + r;
        if (e0 + erow < E) {
          ssum += __expf(sc[i] - m);
          int j = atomicAdd(&cursor[sIdxS[erow]], 1);
          cwt[j] = make_int2(sIdxT[erow], __float_as_int(sc[i]));
        }
      }
    int rid = wv * 4 + quad;
    redM[rid] = m;
    redS[rid] = ssum;
  }
  __syncthreads();
  if (t == 0) {
    float M = redM[0], S = redS[0];
#pragma unroll
    for (int i = 1; i < 16; ++i) {
      float m2 = redM[i], s2 = redS[i];
      float Mn = fmaxf(M, m2);
      S = S * __expf(M - Mn) + s2 * __expf(m2 - Mn);
      M = Mn;
    }
    part[blockIdx.x] = make_float2(M, S);
  }
}

// ---------------------------------------------------------------------------
// K3: final reduce of per-block partials -> MS[0]=M, MS[1]=1/sum
__global__ __launch_bounds__(256) void softmax_final(
    const float2* __restrict__ part, int nPart, float* __restrict__ MS) {
  __shared__ float mS[256], sS[256];
  int tid = threadIdx.x;
  float m = -1e30f, sum = 0.f;
  for (int i = tid; i < nPart; i += 256) {
    float2 p = part[i];
    float M = fmaxf(m, p.x);
    sum = sum * __expf(m - M) + p.y * __expf(p.x - M);
    m = M;
  }
  mS[tid] = m;
  sS[tid] = sum;
  __syncthreads();
  for (int off = 128; off > 0; off >>= 1) {
    if (tid < off) {
      float m1 = mS[tid], s1 = sS[tid];
      float m2 = mS[tid + off], s2 = sS[tid + off];
      float M = fmaxf(m1, m2);
      mS[tid] = M;
      sS[tid] = s1 * __expf(m1 - M) + s2 * __expf(m2 - M);
    }
    __syncthreads();
  }
  if (tid == 0) {
    MS[0] = mS[0];
    MS[1] = 1.f / sS[0];
  }
}

// ---------------------------------------------------------------------------
// CSR scan (exclusive prefix over deg)
__global__ __launch_bounds__(256) void scan1(const int* __restrict__ deg,
                                             int* __restrict__ incl,
                                             int* __restrict__ bsum, int N) {
  __shared__ int sh[256];
  int tid = threadIdx.x;
  int i = blockIdx.x * 256 + tid;
  sh[tid] = (i < N) ? deg[i] : 0;
  __syncthreads();
  for (int off = 1; off < 256; off <<= 1) {
    int tv = (tid >= off) ? sh[tid - off] : 0;
    __syncthreads();
    sh[tid] += tv;
    __syncthreads();
  }
  if (i < N) incl[i] = sh[tid];
  if (tid == 255) bsum[blockIdx.x] = sh[255];
}

__global__ __launch_bounds__(256) void scan2(int* __restrict__ bsum, int nb) {
  __shared__ int sh[256];
  int tid = threadIdx.x;
  sh[tid] = (tid < nb) ? bsum[tid] : 0;
  __syncthreads();
  for (int off = 1; off < 256; off <<= 1) {
    int tv = (tid >= off) ? sh[tid - off] : 0;
    __syncthreads();
    sh[tid] += tv;
    __syncthreads();
  }
  if (tid < nb) bsum[tid] = sh[tid];
}

__global__ __launch_bounds__(256) void scan3(const int* __restrict__ deg,
                                             const int* __restrict__ incl,
                                             const int* __restrict__ bsum,
                                             int* __restrict__ offs,
                                             int* __restrict__ cursor, int N,
                                             int E) {
  int i = blockIdx.x * 256 + threadIdx.x;
  if (i >= N) return;
  int base = (blockIdx.x > 0) ? bsum[blockIdx.x - 1] : 0;
  int ex = incl[i] - deg[i] + base;
  offs[i] = ex;
  cursor[i] = ex;
  if (i == N - 1) offs[N] = E;
}

// ---------------------------------------------------------------------------
// K5: fused gather (bf16 v) + softmax-normalize + layernorm, unroll x4.
__global__ __launch_bounds__(256) void gather_ln(
    const int* __restrict__ offs, const int2* __restrict__ cwt,
    const ushort* __restrict__ vb, const float* __restrict__ MS,
    const float* __restrict__ gamma, const float* __restrict__ beta,
    float* __restrict__ y, int N) {
  int tid = threadIdx.x;
  int n = blockIdx.x * 4 + (tid >> 6);
  if (n >= N) return;  // wave-uniform
  int lane = tid & 63;
  float M = MS[0], inv = MS[1];
  int beg = offs[n], end = offs[n + 1];
  float a0 = 0.f, a1 = 0.f;
  int j = beg;
  for (; j + 4 <= end; j += 4) {
    int2 p0 = cwt[j], p1 = cwt[j + 1], p2 = cwt[j + 2], p3 = cwt[j + 3];
    unsigned u0 = *(const unsigned*)(vb + (size_t)p0.x * 128 + lane * 2);
    unsigned u1 = *(const unsigned*)(vb + (size_t)p1.x * 128 + lane * 2);
    unsigned u2 = *(const unsigned*)(vb + (size_t)p2.x * 128 + lane * 2);
    unsigned u3 = *(const unsigned*)(vb + (size_t)p3.x * 128 + lane * 2);
    float w0 = __expf(__int_as_float(p0.y) - M) * inv;
    float w1 = __expf(__int_as_float(p1.y) - M) * inv;
    float w2 = __expf(__int_as_float(p2.y) - M) * inv;
    float w3 = __expf(__int_as_float(p3.y) - M) * inv;
    a0 += w0 * bf2f(u0 & 0xffffu) + w1 * bf2f(u1 & 0xffffu) +
          w2 * bf2f(u2 & 0xffffu) + w3 * bf2f(u3 & 0xffffu);
    a1 += w0 * bf2f(u0 >> 16) + w1 * bf2f(u1 >> 16) + w2 * bf2f(u2 >> 16) +
          w3 * bf2f(u3 >> 16);
  }
  for (; j < end; ++j) {
    int2 p = cwt[j];
    float w = __expf(__int_as_float(p.y) - M) * inv;
    unsigned u = *(const unsigned*)(vb + (size_t)p.x * 128 + lane * 2);
    a0 += w * bf2f(u & 0xffffu);
    a1 += w * bf2f(u >> 16);
  }
  size_t base = (size_t)n * 128 + lane * 2;
  float2 hv = *(const float2*)(y + base);
  float y0 = hv.x + a0, y1 = hv.y + a1;
  float sum = y0 + y1, ssq = y0 * y0 + y1 * y1;
#pragma unroll
  for (int off = 1; off < 64; off <<= 1) {
    sum += __shfl_xor(sum, off);
    ssq += __shfl_xor(ssq, off);
  }
  float mu = sum * (1.f / 128.f);
  float var = ssq * (1.f / 128.f) - mu * mu;
  float rstd = rsqrtf(var + EPS);
  float2 g = *(const float2*)(gamma + lane * 2);
  float2 bt = *(const float2*)(beta + lane * 2);
  float2 out;
  out.x = g.x * (y0 - mu) * rstd + bt.x;
  out.y = g.y * (y1 - mu) * rstd + bt.y;
  *(float2*)(y + base) = out;
}

// ---------------------------------------------------------------------------
extern "C" void kernel_launch(void* const* d_in, const int* in_sizes, int n_in,
                              void* d_out, int out_size, void* d_ws,
                              size_t ws_size, hipStream_t stream) {
  const float* X  = (const float*)d_in[0];
  const float* EF = (const float*)d_in[1];
  const float* Wn = (const float*)d_in[2];
  const float* bn = (const float*)d_in[3];
  const float* Wq = (const float*)d_in[4];
  const float* bq = (const float*)d_in[5];
  const float* Wk = (const float*)d_in[6];
  const float* bk = (const float*)d_in[7];
  const float* Wv = (const float*)d_in[8];
  const float* bv = (const float*)d_in[9];
  const float* We = (const float*)d_in[10];
  const float* be = (const float*)d_in[11];
  const float* A1 = (const float*)d_in[12];
  const float* b1 = (const float*)d_in[13];
  const float* A2 = (const float*)d_in[14];
  const float* b2 = (const float*)d_in[15];
  const float* gamma = (const float*)d_in[16];
  const float* beta  = (const float*)d_in[17];
  const int* ei = (const int*)d_in[18];

  int N = in_sizes[0] / D;   // 50000
  int E = in_sizes[1] / DE;  // 400000
  const int* src = ei;
  const int* tgt = ei + E;

  float* h = (float*)d_out;  // h accumulated/normalized in place
  float* ws = (float*)d_ws;
  float2* part = (float2*)ws;                          // 4096 cap
  float* MS    = (float*)(part + 4096);                // 4
  float* bfold = MS + 4;                               // 128
  ushort* vb   = (ushort*)(bfold + 128);               // N*128 bf16
  ushort* q2p  = vb + (size_t)N * D;                   // N*128
  ushort* k2p  = q2p + (size_t)N * D;                  // N*128
  ushort* AfqT = k2p + (size_t)N * D;                  // 128*128
  ushort* AfkT = AfqT + 128 * 128;                     // 128*128
  ushort* AfeT = AfkT + 128 * 128;                     // 128*64
  ushort* WnT  = AfeT + 128 * 64;                      // 128*128
  ushort* WvT  = WnT + 128 * 128;                      // 128*128
  int* deg    = (int*)(WvT + 128 * 128);               // N
  int* incl   = deg + N;                               // N
  int* bsum   = incl + N;                              // 256
  int* cursor = bsum + 256;                            // N
  int* offs   = cursor + N;                            // N+2
  int2* cwt   = (int2*)(offs + N + 2);                 // E

  int nbScan = (N + 255) / 256;          // 196 (<= 256)
  int nbEdge = (E + 127) / 128;          // 3125 (<= 4096 part cap)
  int nbHist = (E + 127) / 128;

  hipMemsetAsync(deg, 0, (size_t)N * sizeof(int), stream);
  fold_pack<<<577 + nbHist, 128, 0, stream>>>(Wq, Wk, We, A1, bq, bk, be, b1,
                                              Wn, Wv, AfqT, AfkT, AfeT, bfold,
                                              WnT, WvT, src, deg, E);
  scan1<<<nbScan, 256, 0, stream>>>(deg, incl, bsum, N);
  scan2<<<1, 256, 0, stream>>>(bsum, nbScan);
  scan3<<<nbScan, 256, 0, stream>>>(deg, incl, bsum, offs, cursor, N, E);
  node_gemm_mfma<<<dim3((N + 255) / 256, 4), 256, 0, stream>>>(
      X, WnT, WvT, AfqT, AfkT, bn, bv, h, vb, q2p, k2p, N);
  edge_fused4<<<nbEdge, 256, 0, stream>>>(EF, AfeT, bfold, A2, b2, q2p, k2p,
                                          src, tgt, cursor, cwt, part, E);
  softmax_final<<<1, 256, 0, stream>>>(part, nbEdge, MS);
  gather_ln<<<(N + 3) / 4, 256, 0, stream>>>(offs, cwt, vb, MS, gamma, beta, h,
                                             N);
}